// Round 12
// baseline (235.140 us; speedup 1.0000x reference)
//
#include <hip/hip_runtime.h>
#include <math.h>

#define SLEN 2000
#define BATCH 8
#define MTOK 16000
#define WIN 99
#define XPAD 264

typedef __attribute__((ext_vector_type(8))) short short8;
typedef __attribute__((ext_vector_type(4))) float floatx4;

// ---------- bf16 helpers (bit-level, RNE) ----------
__device__ __forceinline__ float bf2f(unsigned int h) {
  union { unsigned int u; float f; } w; w.u = h << 16; return w.f;
}
__device__ __forceinline__ unsigned short f2bf(float f) {
  union { float f; unsigned int u; } w; w.f = f;
  return (unsigned short)((w.u + 0x7fffu + ((w.u >> 16) & 1u)) >> 16);
}
// 8 fp32 -> bf16x8 A/B fragment (in-register weight conversion)
__device__ __forceinline__ short8 cvt_row8(const float* __restrict__ p) {
  float4 v0 = *(const float4*)p;
  float4 v1 = *(const float4*)(p + 4);
  unsigned short t8[8] = {f2bf(v0.x), f2bf(v0.y), f2bf(v0.z), f2bf(v0.w),
                          f2bf(v1.x), f2bf(v1.y), f2bf(v1.z), f2bf(v1.w)};
  return *(const short8*)t8;
}
// inline positional encoding: sin(ang) for even col, cos(ang) for odd.
// fract-based range reduction keeps v_sin in its safe domain.
__device__ __forceinline__ float posenc_val(int spos, int col) {
  float p   = (float)(col >> 1);
  float dv  = __expf(p * -0.07195578415606394f);   // exp(-p*ln(10000)/128)
  float ang = (float)spos * dv;
  float rev = ang * 0.15915494309189535f;          // /2pi
  rev -= floorf(rev);
  if (col & 1) { rev += 0.25f; rev -= floorf(rev); }  // cos = sin(+1/4 rev)
  return __sinf(rev * 6.283185307179586f);
}

// ================= dispatch 1: fused encoder + qkv =================
// 250 blocks x 256 thr x 64 tokens. Wave w owns cols [64w,64w+64).
// A: src fp32 direct + cvt. B: fp32 weights direct + in-reg cvt (L2-resident).
// posenc inline. Xt (LDS) carries x between stages; xb/qkvb to global.
__global__ __launch_bounds__(256) void k_pre(
    const float* __restrict__ src,
    const float* __restrict__ wenc, const float* __restrict__ benc,
    const float* __restrict__ wqk,  const float* __restrict__ bqk,
    unsigned short* __restrict__ xb, unsigned short* __restrict__ qkvb) {
  __shared__ __align__(16) unsigned short Xt[64 * XPAD];   // 33792 B
  const int tid = threadIdx.x, lane = tid & 63, w = tid >> 6;
  const int m0 = blockIdx.x * 64;
  const int kq = lane >> 4, ml = lane & 15;
  const int wcol = w * 64;

  // ---- stage 1: x = src @ Wenc^T + benc + posenc ----
  floatx4 acc[4][4] = {};
#pragma unroll
  for (int k8 = 0; k8 < 8; ++k8) {
    const int kt = k8 * 32;
    short8 af[4];
#pragma unroll
    for (int mt = 0; mt < 4; ++mt)
      af[mt] = cvt_row8(src + (size_t)(m0 + mt * 16 + ml) * 256 + kt + kq * 8);
#pragma unroll
    for (int nt = 0; nt < 4; ++nt) {
      short8 bf = cvt_row8(wenc + (size_t)(wcol + nt * 16 + ml) * 256 + kt + kq * 8);
#pragma unroll
      for (int mt = 0; mt < 4; ++mt)
        acc[mt][nt] = __builtin_amdgcn_mfma_f32_16x16x32_bf16(af[mt], bf, acc[mt][nt], 0, 0, 0);
    }
  }
#pragma unroll
  for (int mt = 0; mt < 4; ++mt)
#pragma unroll
    for (int nt = 0; nt < 4; ++nt)
#pragma unroll
      for (int r = 0; r < 4; ++r) {
        int lrow = mt * 16 + kq * 4 + r;
        int col  = wcol + nt * 16 + ml;
        int spos = (m0 + lrow) % SLEN;
        float v = acc[mt][nt][r] + benc[col] + posenc_val(spos, col);
        unsigned short hv = f2bf(v);
        Xt[lrow * XPAD + col] = hv;
        xb[(size_t)(m0 + lrow) * 256 + col] = hv;
      }
  __syncthreads();

  // ---- stage 2: qkv = Xt @ Wqk^T + b, 3 passes of 256 cols ----
  for (int p = 0; p < 3; ++p) {
    floatx4 a2[4][4] = {};
#pragma unroll
    for (int k8 = 0; k8 < 8; ++k8) {
      const int kt = k8 * 32;
      short8 af[4];
#pragma unroll
      for (int mt = 0; mt < 4; ++mt)
        af[mt] = *(const short8*)&Xt[(mt * 16 + ml) * XPAD + kt + kq * 8];
#pragma unroll
      for (int nt = 0; nt < 4; ++nt) {
        short8 bf = cvt_row8(wqk + (size_t)(p * 256 + wcol + nt * 16 + ml) * 256 + kt + kq * 8);
#pragma unroll
        for (int mt = 0; mt < 4; ++mt)
          a2[mt][nt] = __builtin_amdgcn_mfma_f32_16x16x32_bf16(af[mt], bf, a2[mt][nt], 0, 0, 0);
      }
    }
#pragma unroll
    for (int mt = 0; mt < 4; ++mt)
#pragma unroll
      for (int nt = 0; nt < 4; ++nt)
#pragma unroll
        for (int r = 0; r < 4; ++r) {
          int row = m0 + mt * 16 + kq * 4 + r;
          int cg  = p * 256 + wcol + nt * 16 + ml;
          qkvb[(size_t)row * 768 + cg] = f2bf(a2[mt][nt][r] + bqk[cg]);
        }
  }
}

// ================= dispatch 2: attention (both heads) + full post chain =================
// grid (32, 8) = 256 blocks x 256 thr. LDS 64768 B static:
//   [0..47872)   KV (attn K then V^T)      -> later Ctx (33792) + LN/head scratch
//   [47872..64768) Ps (bf16 P matrix)      -> free after attention
// O accumulators for both heads live in registers across the head loop, so the
// Ctx LDS write can alias KV after one barrier. Post chain = verified R9 k_post
// with B operands cvt'd from fp32 in-register and headprep computed per block.
#define KPAD 136
#define VPAD 184
#define PPAD 132
#define UNION 176

__global__ __launch_bounds__(256) void k_ap(
    const unsigned short* __restrict__ qkv,
    const unsigned short* __restrict__ xb,
    const float* __restrict__ wout, const float* __restrict__ bout,
    const float* __restrict__ ln1w, const float* __restrict__ ln1b,
    const float* __restrict__ w1,   const float* __restrict__ b1,
    const float* __restrict__ w2,   const float* __restrict__ b2,
    const float* __restrict__ fc1w, const float* __restrict__ fc1b,
    const float* __restrict__ fc2w, const float* __restrict__ fc2b,
    const float* __restrict__ ln2w, const float* __restrict__ ln2b,
    float* __restrict__ out) {
  __shared__ __align__(16) unsigned char smem[64768];
  unsigned short* KV  = (unsigned short*)smem;              // attn
  unsigned short* Ps  = (unsigned short*)(smem + 47872);    // attn
  unsigned short* CX  = (unsigned short*)smem;              // Ctx, then x1, then h
  float* lnred  = (float*)(smem + 33792);                   // [4][64][3]
  float* lnstat = (float*)(smem + 36864);                   // [64][2]
  float* lnp    = (float*)(smem + 37376);                   // ln1 w/b
  float* c1s    = (float*)(smem + 39424);                   // head c1
  float* hpred  = (float*)(smem + 40448);                   // [4][2] headprep partials
  float* hpc    = (float*)(smem + 40480);                   // c0, sum(c1)

  const int tid = threadIdx.x, lane = tid & 63, w = tid >> 6;
  const int i0 = blockIdx.x * 64;
  const int b  = blockIdx.y;
  const int jmin_u = i0 - WIN;
  const int kq = lane >> 4, ml = lane & 15;
  const float scale = 0.08838834764831845f;

  // =============== attention, both heads, O in registers ===============
  floatx4 ovh[2][8];
  for (int h = 0; h < 2; ++h) {
    if (h) __syncthreads();   // KV/Ps reuse across heads

    const int qrow = i0 + w * 16 + ml;
    const unsigned short* qptr =
        qkv + (size_t)(b * SLEN + min(qrow, SLEN - 1)) * 768 + h * 128 + kq * 8;
    short8 qf[4];
#pragma unroll
    for (int kc = 0; kc < 4; ++kc) qf[kc] = *(const short8*)(qptr + kc * 32);

    for (int it = 0; it < 11; ++it) {
      int idx = it * 256 + tid;
      int row = idx >> 4;
      int c8  = idx & 15;
      int j = jmin_u + row;
      uint4 v = make_uint4(0u, 0u, 0u, 0u);
      if (j >= 0 && j < SLEN)
        v = *(const uint4*)(qkv + (size_t)(b * SLEN + j) * 768 + 256 + h * 128 + c8 * 8);
      *(uint4*)&KV[row * KPAD + c8 * 8] = v;
    }
    __syncthreads();

    const int koff = w * 16;
    floatx4 sc[8] = {};
#pragma unroll
    for (int kt = 0; kt < 8; ++kt) {
#pragma unroll
      for (int kc = 0; kc < 4; ++kc) {
        short8 kf = *(const short8*)&KV[(koff + kt * 16 + ml) * KPAD + kc * 32 + kq * 8];
        sc[kt] = __builtin_amdgcn_mfma_f32_16x16x32_bf16(qf[kc], kf, sc[kt], 0, 0, 0);
      }
    }

    const int qme = i0 + w * 16 + kq * 4;
    const int jme = jmin_u + koff + ml;
    float mx[4] = {-1e30f, -1e30f, -1e30f, -1e30f};
#pragma unroll
    for (int kt = 0; kt < 8; ++kt)
#pragma unroll
      for (int r = 0; r < 4; ++r) {
        int j = jme + kt * 16, q = qme + r;
        bool ok = (j >= 0) && (j >= q - WIN) && (j <= q);
        float s = ok ? sc[kt][r] : -1e30f;
        sc[kt][r] = s;
        mx[r] = fmaxf(mx[r], s);
      }
#pragma unroll
    for (int r = 0; r < 4; ++r)
#pragma unroll
      for (int off = 8; off; off >>= 1) mx[r] = fmaxf(mx[r], __shfl_xor(mx[r], off, 16));

    float sum[4] = {0.f, 0.f, 0.f, 0.f};
#pragma unroll
    for (int kt = 0; kt < 8; ++kt)
#pragma unroll
      for (int r = 0; r < 4; ++r) {
        float e = __expf((sc[kt][r] - mx[r]) * scale);
        sc[kt][r] = e;
        sum[r] += e;
      }
#pragma unroll
    for (int r = 0; r < 4; ++r)
#pragma unroll
      for (int off = 8; off; off >>= 1) sum[r] += __shfl_xor(sum[r], off, 16);
    float rinv[4];
#pragma unroll
    for (int r = 0; r < 4; ++r) rinv[r] = 1.f / sum[r];

    unsigned short* pw = Ps + w * (16 * PPAD);
#pragma unroll
    for (int kt = 0; kt < 8; ++kt)
#pragma unroll
      for (int r = 0; r < 4; ++r)
        pw[(kq * 4 + r) * PPAD + kt * 16 + ml] = f2bf(sc[kt][r]);
    __syncthreads();   // K reads done before V overwrite

    for (int it = 0; it < 12; ++it) {
      int idx = it * 256 + tid;
      int grp = idx >> 6;
      int key = (grp >> 4) * 64 + (idx & 63);
      int c8  = grp & 15;
      if (key < UNION) {
        int j = jmin_u + key;
        uint4 v = make_uint4(0u, 0u, 0u, 0u);
        if (j >= 0 && j < SLEN)
          v = *(const uint4*)(qkv + (size_t)(b * SLEN + j) * 768 + 512 + h * 128 + c8 * 8);
        unsigned short e[8];
        *(uint4*)e = v;
        int d0 = c8 * 8;
#pragma unroll
        for (int i = 0; i < 8; ++i) KV[(d0 + i) * VPAD + key] = e[i];
      }
    }
    __syncthreads();

#pragma unroll
    for (int dt = 0; dt < 8; ++dt) ovh[h][dt] = (floatx4){0.f, 0.f, 0.f, 0.f};
#pragma unroll
    for (int kc = 0; kc < 4; ++kc) {
      short8 pf = *(const short8*)&pw[ml * PPAD + kc * 32 + kq * 8];
#pragma unroll
      for (int dt = 0; dt < 8; ++dt) {
        short8 vf = *(const short8*)&KV[(dt * 16 + ml) * VPAD + koff + kc * 32 + kq * 8];
        ovh[h][dt] = __builtin_amdgcn_mfma_f32_16x16x32_bf16(pf, vf, ovh[h][dt], 0, 0, 0);
      }
    }
#pragma unroll
    for (int dt = 0; dt < 8; ++dt)
#pragma unroll
      for (int r = 0; r < 4; ++r) ovh[h][dt][r] *= rinv[r];
  }
  __syncthreads();   // all PV reads of KV done before Ctx aliases it

  // =============== Ctx -> LDS + per-block headprep ===============
#pragma unroll
  for (int h = 0; h < 2; ++h)
#pragma unroll
    for (int dt = 0; dt < 8; ++dt)
#pragma unroll
      for (int r = 0; r < 4; ++r)
        CX[(w * 16 + kq * 4 + r) * XPAD + h * 128 + dt * 16 + ml] = f2bf(ovh[h][dt][r]);
  lnp[tid] = ln1w[tid];
  lnp[256 + tid] = ln1b[tid];
  {
    float we = 0.f;
#pragma unroll 8
    for (int o = 0; o < 64; ++o) we += fc2w[o] * fc1w[o * 256 + tid];
    float c1 = ln2w[tid] * we;
    c1s[tid] = c1;
    float p0 = ln2b[tid] * we;
    if (tid < 64) p0 += fc2w[tid] * fc1b[tid];
    float s0 = p0, s1 = c1;
#pragma unroll
    for (int off = 32; off; off >>= 1) {
      s0 += __shfl_xor(s0, off);
      s1 += __shfl_xor(s1, off);
    }
    if (lane == 0) { hpred[w * 2] = s0; hpred[w * 2 + 1] = s1; }
  }
  __syncthreads();   // Ctx + c1s + partials visible

  // =============== stage A: o = ctx@Wout^T + bout + x -> LN1 ===============
  const int wcol = w * 64;
  floatx4 acc[4][4] = {};
#pragma unroll
  for (int k8 = 0; k8 < 8; ++k8) {
    const int kt = k8 * 32;
    short8 af[4];
#pragma unroll
    for (int mt = 0; mt < 4; ++mt)
      af[mt] = *(const short8*)&CX[(mt * 16 + ml) * XPAD + kt + kq * 8];
#pragma unroll
    for (int nt = 0; nt < 4; ++nt) {
      short8 bf = cvt_row8(wout + (size_t)(wcol + nt * 16 + ml) * 256 + kt + kq * 8);
#pragma unroll
      for (int mt = 0; mt < 4; ++mt)
        acc[mt][nt] = __builtin_amdgcn_mfma_f32_16x16x32_bf16(af[mt], bf, acc[mt][nt], 0, 0, 0);
    }
  }
  float s_[4][4], q_[4][4];
#pragma unroll
  for (int mt = 0; mt < 4; ++mt)
#pragma unroll
    for (int r = 0; r < 4; ++r) { s_[mt][r] = 0.f; q_[mt][r] = 0.f; }
#pragma unroll
  for (int mt = 0; mt < 4; ++mt)
#pragma unroll
    for (int nt = 0; nt < 4; ++nt)
#pragma unroll
      for (int r = 0; r < 4; ++r) {
        int lrow = mt * 16 + kq * 4 + r;
        int rm   = min(i0 + lrow, SLEN - 1);
        int col  = wcol + nt * 16 + ml;
        float v = acc[mt][nt][r] + bout[col]
                + bf2f(xb[(size_t)(b * SLEN + rm) * 256 + col]);
        acc[mt][nt][r] = v;
        s_[mt][r] += v;
        q_[mt][r] += v * v;
      }
#pragma unroll
  for (int mt = 0; mt < 4; ++mt)
#pragma unroll
    for (int r = 0; r < 4; ++r) {
#pragma unroll
      for (int off = 8; off; off >>= 1) {
        s_[mt][r] += __shfl_xor(s_[mt][r], off, 16);
        q_[mt][r] += __shfl_xor(q_[mt][r], off, 16);
      }
      if (ml == 0) {
        int lrow = mt * 16 + kq * 4 + r;
        lnred[(w * 64 + lrow) * 3 + 0] = s_[mt][r];
        lnred[(w * 64 + lrow) * 3 + 1] = q_[mt][r];
      }
    }
  __syncthreads();   // MFMAs + partials done (CX safe to overwrite after)
  if (tid < 64) {
    float s = 0.f, q = 0.f;
#pragma unroll
    for (int i = 0; i < 4; ++i) {
      s += lnred[(i * 64 + tid) * 3 + 0];
      q += lnred[(i * 64 + tid) * 3 + 1];
    }
    float mu  = s * (1.f / 256.f);
    float var = q * (1.f / 256.f) - mu * mu;
    lnstat[tid * 2 + 0] = mu;
    lnstat[tid * 2 + 1] = rsqrtf(var + 1e-5f);
  }
  if (tid == 64) {
    hpc[0] = hpred[0] + hpred[2] + hpred[4] + hpred[6] + fc2b[0];
    hpc[1] = hpred[1] + hpred[3] + hpred[5] + hpred[7];
  }
  __syncthreads();
  floatx4 x1sav[4][4];
#pragma unroll
  for (int mt = 0; mt < 4; ++mt)
#pragma unroll
    for (int r = 0; r < 4; ++r) {
      int lrow = mt * 16 + kq * 4 + r;
      float mu = lnstat[lrow * 2], rr = lnstat[lrow * 2 + 1];
#pragma unroll
      for (int nt = 0; nt < 4; ++nt) {
        int col = wcol + nt * 16 + ml;
        float x1 = (acc[mt][nt][r] - mu) * rr * lnp[col] + lnp[256 + col];
        x1sav[mt][nt][r] = x1;
        CX[lrow * XPAD + col] = f2bf(x1);
      }
    }
  __syncthreads();   // x1 visible

  // =============== stage B: h = relu(x1@W1^T + b1) ===============
#pragma unroll
  for (int mt = 0; mt < 4; ++mt)
#pragma unroll
    for (int nt = 0; nt < 4; ++nt) acc[mt][nt] = (floatx4){0.f, 0.f, 0.f, 0.f};
#pragma unroll
  for (int k8 = 0; k8 < 8; ++k8) {
    const int kt = k8 * 32;
    short8 af[4];
#pragma unroll
    for (int mt = 0; mt < 4; ++mt)
      af[mt] = *(const short8*)&CX[(mt * 16 + ml) * XPAD + kt + kq * 8];
#pragma unroll
    for (int nt = 0; nt < 4; ++nt) {
      short8 bf = cvt_row8(w1 + (size_t)(wcol + nt * 16 + ml) * 256 + kt + kq * 8);
#pragma unroll
      for (int mt = 0; mt < 4; ++mt)
        acc[mt][nt] = __builtin_amdgcn_mfma_f32_16x16x32_bf16(af[mt], bf, acc[mt][nt], 0, 0, 0);
    }
  }
  __syncthreads();   // x1 reads done
#pragma unroll
  for (int mt = 0; mt < 4; ++mt)
#pragma unroll
    for (int nt = 0; nt < 4; ++nt)
#pragma unroll
      for (int r = 0; r < 4; ++r) {
        int lrow = mt * 16 + kq * 4 + r;
        int col  = wcol + nt * 16 + ml;
        CX[lrow * XPAD + col] = f2bf(fmaxf(acc[mt][nt][r] + b1[col], 0.f));
      }
  __syncthreads();   // h visible

  // =============== stage C: o = h@W2^T + b2 + x1 -> LN2 + head ===============
#pragma unroll
  for (int mt = 0; mt < 4; ++mt)
#pragma unroll
    for (int nt = 0; nt < 4; ++nt) acc[mt][nt] = (floatx4){0.f, 0.f, 0.f, 0.f};
#pragma unroll
  for (int k8 = 0; k8 < 8; ++k8) {
    const int kt = k8 * 32;
    short8 af[4];
#pragma unroll
    for (int mt = 0; mt < 4; ++mt)
      af[mt] = *(const short8*)&CX[(mt * 16 + ml) * XPAD + kt + kq * 8];
#pragma unroll
    for (int nt = 0; nt < 4; ++nt) {
      short8 bf = cvt_row8(w2 + (size_t)(wcol + nt * 16 + ml) * 256 + kt + kq * 8);
#pragma unroll
      for (int mt = 0; mt < 4; ++mt)
        acc[mt][nt] = __builtin_amdgcn_mfma_f32_16x16x32_bf16(af[mt], bf, acc[mt][nt], 0, 0, 0);
    }
  }
  float ss[4][4], qq[4][4], dd[4][4];
#pragma unroll
  for (int mt = 0; mt < 4; ++mt)
#pragma unroll
    for (int r = 0; r < 4; ++r) { ss[mt][r] = 0.f; qq[mt][r] = 0.f; dd[mt][r] = 0.f; }
#pragma unroll
  for (int mt = 0; mt < 4; ++mt)
#pragma unroll
    for (int nt = 0; nt < 4; ++nt)
#pragma unroll
      for (int r = 0; r < 4; ++r) {
        int col = wcol + nt * 16 + ml;
        float v = acc[mt][nt][r] + b2[col] + x1sav[mt][nt][r];
        ss[mt][r] += v;
        qq[mt][r] += v * v;
        dd[mt][r] += v * c1s[col];
      }
#pragma unroll
  for (int mt = 0; mt < 4; ++mt)
#pragma unroll
    for (int r = 0; r < 4; ++r) {
#pragma unroll
      for (int off = 8; off; off >>= 1) {
        ss[mt][r] += __shfl_xor(ss[mt][r], off, 16);
        qq[mt][r] += __shfl_xor(qq[mt][r], off, 16);
        dd[mt][r] += __shfl_xor(dd[mt][r], off, 16);
      }
      if (ml == 0) {
        int lrow = mt * 16 + kq * 4 + r;
        lnred[(w * 64 + lrow) * 3 + 0] = ss[mt][r];
        lnred[(w * 64 + lrow) * 3 + 1] = qq[mt][r];
        lnred[(w * 64 + lrow) * 3 + 2] = dd[mt][r];
      }
    }
  __syncthreads();
  if (tid < 64 && i0 + tid < SLEN) {
    float s = 0.f, q = 0.f, d = 0.f;
#pragma unroll
    for (int i = 0; i < 4; ++i) {
      s += lnred[(i * 64 + tid) * 3 + 0];
      q += lnred[(i * 64 + tid) * 3 + 1];
      d += lnred[(i * 64 + tid) * 3 + 2];
    }
    float mu  = s * (1.f / 256.f);
    float var = q * (1.f / 256.f) - mu * mu;
    float rr  = rsqrtf(var + 1e-5f);
    out[(size_t)b * SLEN + i0 + tid] = rr * (d - mu * hpc[1]) + hpc[0];
  }
}

extern "C" void kernel_launch(void* const* d_in, const int* in_sizes, int n_in,
                              void* d_out, int out_size, void* d_ws, size_t ws_size,
                              hipStream_t stream) {
  const float* src        = (const float*)d_in[0];
  // d_in[1] = input_lengths (unused)
  const float* W_enc      = (const float*)d_in[2];
  const float* b_enc      = (const float*)d_in[3];
  const float* in_proj_w  = (const float*)d_in[4];
  const float* in_proj_b  = (const float*)d_in[5];
  const float* out_proj_w = (const float*)d_in[6];
  const float* out_proj_b = (const float*)d_in[7];
  const float* ln1_w      = (const float*)d_in[8];
  const float* ln1_b      = (const float*)d_in[9];
  const float* lin1_w     = (const float*)d_in[10];
  const float* lin1_b     = (const float*)d_in[11];
  const float* lin2_w     = (const float*)d_in[12];
  const float* lin2_b     = (const float*)d_in[13];
  const float* ln2_w      = (const float*)d_in[14];
  const float* ln2_b      = (const float*)d_in[15];
  const float* fc1_w      = (const float*)d_in[16];
  const float* fc1_b      = (const float*)d_in[17];
  const float* fc2_w      = (const float*)d_in[18];
  const float* fc2_b      = (const float*)d_in[19];

  char* p = (char*)d_ws;
  unsigned short* xb   = (unsigned short*)p;  p += (size_t)MTOK * 256 * 2;
  unsigned short* qkvb = (unsigned short*)p;  p += (size_t)MTOK * 768 * 2;
  // total ~33 MB

  // dispatch 1: encoder + qkv (posenc inline, fp32 weights cvt'd in-register)
  k_pre<<<MTOK / 64, 256, 0, stream>>>(src, W_enc, b_enc, in_proj_w, in_proj_b, xb, qkvb);
  // dispatch 2: attention (both heads) + o-proj + LN1 + FFN + LN2 + head
  k_ap<<<dim3((SLEN + 63) / 64, BATCH), 256, 0, stream>>>(
      qkvb, xb, out_proj_w, out_proj_b, ln1_w, ln1_b,
      lin1_w, lin1_b, lin2_w, lin2_b,
      fc1_w, fc1_b, fc2_w, fc2_b, ln2_w, ln2_b, (float*)d_out);
}

// Round 13
// 179.783 us; speedup vs baseline: 1.3079x; 1.3079x over previous
//
#include <hip/hip_runtime.h>
#include <math.h>

#define SLEN 2000
#define BATCH 8
#define MTOK 16000
#define WIN 99
#define XPAD 264

typedef __attribute__((ext_vector_type(8))) short short8;
typedef __attribute__((ext_vector_type(4))) float floatx4;

#define WAITVM0() __builtin_amdgcn_s_waitcnt(0x0F70)
#define WAITVM4() __builtin_amdgcn_s_waitcnt(0x0F74)

// ---------- bf16 helpers (bit-level, RNE) ----------
__device__ __forceinline__ float bf2f(unsigned int h) {
  union { unsigned int u; float f; } w; w.u = h << 16; return w.f;
}
__device__ __forceinline__ unsigned short f2bf(float f) {
  union { float f; unsigned int u; } w; w.f = f;
  return (unsigned short)((w.u + 0x7fffu + ((w.u >> 16) & 1u)) >> 16);
}

// async global->LDS, 16B per lane; lds base must be wave-uniform
typedef const __attribute__((address_space(1))) unsigned int* gas_t;
typedef __attribute__((address_space(3))) unsigned int* las_t;
__device__ __forceinline__ void gload_lds16(const unsigned short* g, unsigned short* l) {
  __builtin_amdgcn_global_load_lds((gas_t)g, (las_t)l, 16, 0, 0);
}

// inline positional encoding (verified R12): sin for even col, cos for odd
__device__ __forceinline__ float posenc_val(int spos, int col) {
  float p   = (float)(col >> 1);
  float dv  = __expf(p * -0.07195578415606394f);
  float ang = (float)spos * dv;
  float rev = ang * 0.15915494309189535f;
  rev -= floorf(rev);
  if (col & 1) { rev += 0.25f; rev -= floorf(rev); }
  return __sinf(rev * 6.283185307179586f);
}

// ================= dispatch 1: weight cvt only (448 blocks) =================
__device__ __forceinline__ void cvt4(const float* __restrict__ in,
                                     unsigned short* __restrict__ out, int i) {
  float4 v = ((const float4*)in)[i];
  ushort4 o;
  o.x = f2bf(v.x); o.y = f2bf(v.y); o.z = f2bf(v.z); o.w = f2bf(v.w);
  ((ushort4*)out)[i] = o;
}

__global__ __launch_bounds__(256) void k_prep(
    const float* __restrict__ wenc, unsigned short* __restrict__ wencb,
    const float* __restrict__ wqk,  unsigned short* __restrict__ wqkb,
    const float* __restrict__ wout, unsigned short* __restrict__ woutb,
    const float* __restrict__ wl1,  unsigned short* __restrict__ wl1b,
    const float* __restrict__ wl2,  unsigned short* __restrict__ wl2b) {
  const int bx = blockIdx.x, tid = threadIdx.x;
  if (bx < 64)       { cvt4(wenc, wencb, bx * 256 + tid); }
  else if (bx < 256) { cvt4(wqk,  wqkb,  (bx - 64) * 256 + tid); }
  else if (bx < 320) { cvt4(wout, woutb, (bx - 256) * 256 + tid); }
  else if (bx < 384) { cvt4(wl1,  wl1b,  (bx - 320) * 256 + tid); }
  else               { cvt4(wl2,  wl2b,  (bx - 384) * 256 + tid); }
}

// ================= dispatch 2: fused encoder + qkv (R9 verbatim + inline posenc) =================
__global__ __launch_bounds__(256) void k_pre(
    const float* __restrict__ src,
    const unsigned short* __restrict__ wenc, const float* __restrict__ benc,
    const unsigned short* __restrict__ wqk, const float* __restrict__ bqk,
    unsigned short* __restrict__ xb, unsigned short* __restrict__ qkvb) {
  __shared__ __align__(16) unsigned short Xt[64 * XPAD];       // 33792 B
  __shared__ __align__(16) unsigned short Bst[4][2][2048];     // 32768 B
  const int tid = threadIdx.x, lane = tid & 63, w = tid >> 6;
  const int m0 = blockIdx.x * 64;
  const int kq = lane >> 4, ml = lane & 15;
  const int wcolg = w * 64;

  int grow[4], gsc[4];
#pragma unroll
  for (int i = 0; i < 4; ++i) {
    grow[i] = i * 16 + (lane >> 2);
    gsc[i]  = (lane & 3) ^ ((grow[i] >> 1) & 3);
  }

  auto issueB = [&](const unsigned short* W, int kt, int buf) {
#pragma unroll
    for (int i = 0; i < 4; ++i)
      gload_lds16(W + (size_t)(wcolg + grow[i]) * 256 + kt + gsc[i] * 8,
                  &Bst[w][buf][i * 512]);
  };
  auto readB = [&](int buf, int nt) -> short8 {
    int n = nt * 16 + ml;
    int sb = kq ^ ((n >> 1) & 3);
    return *(const short8*)&Bst[w][buf][n * 32 + sb * 8];
  };

  // ---- stage 1: x = src @ Wenc^T ----
  floatx4 acc[4][4] = {};
#pragma unroll
  for (int k8 = 0; k8 < 8; ++k8) {
    const int kt = k8 * 32;
    issueB(wenc, kt, k8 & 1);
    short8 af[4];
#pragma unroll
    for (int mt = 0; mt < 4; ++mt) {
      const float* ap = src + (size_t)(m0 + mt * 16 + ml) * 256 + kt + kq * 8;
      float4 v0 = *(const float4*)ap;
      float4 v1 = *(const float4*)(ap + 4);
      unsigned short t8[8] = {f2bf(v0.x), f2bf(v0.y), f2bf(v0.z), f2bf(v0.w),
                              f2bf(v1.x), f2bf(v1.y), f2bf(v1.z), f2bf(v1.w)};
      af[mt] = *(const short8*)t8;
    }
    WAITVM0();
#pragma unroll
    for (int nt = 0; nt < 4; ++nt) {
      short8 bf = readB(k8 & 1, nt);
#pragma unroll
      for (int mt = 0; mt < 4; ++mt)
        acc[mt][nt] = __builtin_amdgcn_mfma_f32_16x16x32_bf16(af[mt], bf, acc[mt][nt], 0, 0, 0);
    }
  }
  // epilogue -> Xt (LDS) + xb (global), posenc inline
#pragma unroll
  for (int mt = 0; mt < 4; ++mt)
#pragma unroll
    for (int nt = 0; nt < 4; ++nt)
#pragma unroll
      for (int r = 0; r < 4; ++r) {
        int lrow = mt * 16 + kq * 4 + r;
        int col  = wcolg + nt * 16 + ml;
        int spos = (m0 + lrow) % SLEN;
        float v = acc[mt][nt][r] + benc[col] + posenc_val(spos, col);
        unsigned short hv = f2bf(v);
        Xt[lrow * XPAD + col] = hv;
        xb[(size_t)(m0 + lrow) * 256 + col] = hv;
      }
  __syncthreads();

  // ---- stage 2: qkv = Xt @ Wqk^T, 3 passes, 2-deep B prefetch ----
  for (int p = 0; p < 3; ++p) {
    const unsigned short* Wp = wqk + (size_t)p * 65536;
    floatx4 a2[4][4] = {};
    issueB(Wp, 0, 0);
#pragma unroll
    for (int k8 = 0; k8 < 7; ++k8) {
      issueB(Wp, (k8 + 1) * 32, (k8 + 1) & 1);
      WAITVM4();
      short8 af[4];
#pragma unroll
      for (int mt = 0; mt < 4; ++mt)
        af[mt] = *(const short8*)&Xt[(mt * 16 + ml) * XPAD + k8 * 32 + kq * 8];
#pragma unroll
      for (int nt = 0; nt < 4; ++nt) {
        short8 bf = readB(k8 & 1, nt);
#pragma unroll
        for (int mt = 0; mt < 4; ++mt)
          a2[mt][nt] = __builtin_amdgcn_mfma_f32_16x16x32_bf16(af[mt], bf, a2[mt][nt], 0, 0, 0);
      }
    }
    WAITVM0();
    {
      short8 af[4];
#pragma unroll
      for (int mt = 0; mt < 4; ++mt)
        af[mt] = *(const short8*)&Xt[(mt * 16 + ml) * XPAD + 224 + kq * 8];
#pragma unroll
      for (int nt = 0; nt < 4; ++nt) {
        short8 bf = readB(1, nt);
#pragma unroll
        for (int mt = 0; mt < 4; ++mt)
          a2[mt][nt] = __builtin_amdgcn_mfma_f32_16x16x32_bf16(af[mt], bf, a2[mt][nt], 0, 0, 0);
      }
    }
#pragma unroll
    for (int mt = 0; mt < 4; ++mt)
#pragma unroll
      for (int nt = 0; nt < 4; ++nt)
#pragma unroll
        for (int r = 0; r < 4; ++r) {
          int row = m0 + mt * 16 + kq * 4 + r;
          int cg  = p * 256 + wcolg + nt * 16 + ml;
          qkvb[(size_t)row * 768 + cg] = f2bf(a2[mt][nt][r] + bqk[cg]);
        }
  }
}

// ================= dispatch 3: attention (2 heads, serial) + post chain =================
// grid (32, 8) x 256 thr, 64768 B static LDS (R12-verified structure), but post
// B operands are PRE-CONVERTED bf16 (the R12 regression was fp32 in-reg cvt).
#define KPAD 136
#define VPAD 184
#define PPAD 132
#define UNION 176

__global__ __launch_bounds__(256) void k_ap(
    const unsigned short* __restrict__ qkv,
    const unsigned short* __restrict__ xb,
    const unsigned short* __restrict__ wout, const float* __restrict__ bout,
    const float* __restrict__ ln1w, const float* __restrict__ ln1b,
    const unsigned short* __restrict__ w1, const float* __restrict__ b1,
    const unsigned short* __restrict__ w2, const float* __restrict__ b2,
    const float* __restrict__ fc1w, const float* __restrict__ fc1b,
    const float* __restrict__ fc2w, const float* __restrict__ fc2b,
    const float* __restrict__ ln2w, const float* __restrict__ ln2b,
    float* __restrict__ out) {
  __shared__ __align__(16) unsigned char smem[64768];
  unsigned short* KV  = (unsigned short*)smem;
  unsigned short* Ps  = (unsigned short*)(smem + 47872);
  unsigned short* CX  = (unsigned short*)smem;              // Ctx, then x1, then h
  float* lnred  = (float*)(smem + 33792);                   // [4][64][3]
  float* lnstat = (float*)(smem + 36864);                   // [64][2]
  float* lnp    = (float*)(smem + 37376);
  float* c1s    = (float*)(smem + 39424);
  float* hpred  = (float*)(smem + 40448);
  float* hpc    = (float*)(smem + 40480);

  const int tid = threadIdx.x, lane = tid & 63, w = tid >> 6;
  const int i0 = blockIdx.x * 64;
  const int b  = blockIdx.y;
  const int jmin_u = i0 - WIN;
  const int kq = lane >> 4, ml = lane & 15;
  const float scale = 0.08838834764831845f;

  // =============== attention, both heads, O in registers ===============
  floatx4 ovh[2][8];
  for (int h = 0; h < 2; ++h) {
    if (h) __syncthreads();

    const int qrow = i0 + w * 16 + ml;
    const unsigned short* qptr =
        qkv + (size_t)(b * SLEN + min(qrow, SLEN - 1)) * 768 + h * 128 + kq * 8;
    short8 qf[4];
#pragma unroll
    for (int kc = 0; kc < 4; ++kc) qf[kc] = *(const short8*)(qptr + kc * 32);

    for (int it = 0; it < 11; ++it) {
      int idx = it * 256 + tid;
      int row = idx >> 4;
      int c8  = idx & 15;
      int j = jmin_u + row;
      uint4 v = make_uint4(0u, 0u, 0u, 0u);
      if (j >= 0 && j < SLEN)
        v = *(const uint4*)(qkv + (size_t)(b * SLEN + j) * 768 + 256 + h * 128 + c8 * 8);
      *(uint4*)&KV[row * KPAD + c8 * 8] = v;
    }
    __syncthreads();

    const int koff = w * 16;
    floatx4 sc[8] = {};
#pragma unroll
    for (int kt = 0; kt < 8; ++kt)
#pragma unroll
      for (int kc = 0; kc < 4; ++kc) {
        short8 kf = *(const short8*)&KV[(koff + kt * 16 + ml) * KPAD + kc * 32 + kq * 8];
        sc[kt] = __builtin_amdgcn_mfma_f32_16x16x32_bf16(qf[kc], kf, sc[kt], 0, 0, 0);
      }

    const int qme = i0 + w * 16 + kq * 4;
    const int jme = jmin_u + koff + ml;
    float mx[4] = {-1e30f, -1e30f, -1e30f, -1e30f};
#pragma unroll
    for (int kt = 0; kt < 8; ++kt)
#pragma unroll
      for (int r = 0; r < 4; ++r) {
        int j = jme + kt * 16, q = qme + r;
        bool ok = (j >= 0) && (j >= q - WIN) && (j <= q);
        float s = ok ? sc[kt][r] : -1e30f;
        sc[kt][r] = s;
        mx[r] = fmaxf(mx[r], s);
      }
#pragma unroll
    for (int r = 0; r < 4; ++r)
#pragma unroll
      for (int off = 8; off; off >>= 1) mx[r] = fmaxf(mx[r], __shfl_xor(mx[r], off, 16));

    float sum[4] = {0.f, 0.f, 0.f, 0.f};
#pragma unroll
    for (int kt = 0; kt < 8; ++kt)
#pragma unroll
      for (int r = 0; r < 4; ++r) {
        float e = __expf((sc[kt][r] - mx[r]) * scale);
        sc[kt][r] = e;
        sum[r] += e;
      }
#pragma unroll
    for (int r = 0; r < 4; ++r)
#pragma unroll
      for (int off = 8; off; off >>= 1) sum[r] += __shfl_xor(sum[r], off, 16);
    float rinv[4];
#pragma unroll
    for (int r = 0; r < 4; ++r) rinv[r] = 1.f / sum[r];

    unsigned short* pw = Ps + w * (16 * PPAD);
#pragma unroll
    for (int kt = 0; kt < 8; ++kt)
#pragma unroll
      for (int r = 0; r < 4; ++r)
        pw[(kq * 4 + r) * PPAD + kt * 16 + ml] = f2bf(sc[kt][r]);
    __syncthreads();

    for (int it = 0; it < 12; ++it) {
      int idx = it * 256 + tid;
      int grp = idx >> 6;
      int key = (grp >> 4) * 64 + (idx & 63);
      int c8  = grp & 15;
      if (key < UNION) {
        int j = jmin_u + key;
        uint4 v = make_uint4(0u, 0u, 0u, 0u);
        if (j >= 0 && j < SLEN)
          v = *(const uint4*)(qkv + (size_t)(b * SLEN + j) * 768 + 512 + h * 128 + c8 * 8);
        unsigned short e[8];
        *(uint4*)e = v;
        int d0 = c8 * 8;
#pragma unroll
        for (int i = 0; i < 8; ++i) KV[(d0 + i) * VPAD + key] = e[i];
      }
    }
    __syncthreads();

#pragma unroll
    for (int dt = 0; dt < 8; ++dt) ovh[h][dt] = (floatx4){0.f, 0.f, 0.f, 0.f};
#pragma unroll
    for (int kc = 0; kc < 4; ++kc) {
      short8 pf = *(const short8*)&pw[ml * PPAD + kc * 32 + kq * 8];
#pragma unroll
      for (int dt = 0; dt < 8; ++dt) {
        short8 vf = *(const short8*)&KV[(dt * 16 + ml) * VPAD + koff + kc * 32 + kq * 8];
        ovh[h][dt] = __builtin_amdgcn_mfma_f32_16x16x32_bf16(pf, vf, ovh[h][dt], 0, 0, 0);
      }
    }
#pragma unroll
    for (int dt = 0; dt < 8; ++dt)
#pragma unroll
      for (int r = 0; r < 4; ++r) ovh[h][dt][r] *= rinv[r];
  }
  __syncthreads();

  // =============== Ctx -> LDS + per-block headprep ===============
#pragma unroll
  for (int h = 0; h < 2; ++h)
#pragma unroll
    for (int dt = 0; dt < 8; ++dt)
#pragma unroll
      for (int r = 0; r < 4; ++r)
        CX[(w * 16 + kq * 4 + r) * XPAD + h * 128 + dt * 16 + ml] = f2bf(ovh[h][dt][r]);
  lnp[tid] = ln1w[tid];
  lnp[256 + tid] = ln1b[tid];
  {
    float we = 0.f;
#pragma unroll 8
    for (int o = 0; o < 64; ++o) we += fc2w[o] * fc1w[o * 256 + tid];
    float c1 = ln2w[tid] * we;
    c1s[tid] = c1;
    float p0 = ln2b[tid] * we;
    if (tid < 64) p0 += fc2w[tid] * fc1b[tid];
    float s0 = p0, s1 = c1;
#pragma unroll
    for (int off = 32; off; off >>= 1) {
      s0 += __shfl_xor(s0, off);
      s1 += __shfl_xor(s1, off);
    }
    if (lane == 0) { hpred[w * 2] = s0; hpred[w * 2 + 1] = s1; }
  }
  __syncthreads();

  // =============== stage A: o = ctx@Wout^T + bout + x -> LN1 ===============
  const int wcol = w * 64;
  floatx4 acc[4][4] = {};
#pragma unroll
  for (int k8 = 0; k8 < 8; ++k8) {
    const int kt = k8 * 32;
    short8 af[4];
#pragma unroll
    for (int mt = 0; mt < 4; ++mt)
      af[mt] = *(const short8*)&CX[(mt * 16 + ml) * XPAD + kt + kq * 8];
#pragma unroll
    for (int nt = 0; nt < 4; ++nt) {
      short8 bf = *(const short8*)(wout + (size_t)(wcol + nt * 16 + ml) * 256 + kt + kq * 8);
#pragma unroll
      for (int mt = 0; mt < 4; ++mt)
        acc[mt][nt] = __builtin_amdgcn_mfma_f32_16x16x32_bf16(af[mt], bf, acc[mt][nt], 0, 0, 0);
    }
  }
  float s_[4][4], q_[4][4];
#pragma unroll
  for (int mt = 0; mt < 4; ++mt)
#pragma unroll
    for (int r = 0; r < 4; ++r) { s_[mt][r] = 0.f; q_[mt][r] = 0.f; }
#pragma unroll
  for (int mt = 0; mt < 4; ++mt)
#pragma unroll
    for (int nt = 0; nt < 4; ++nt)
#pragma unroll
      for (int r = 0; r < 4; ++r) {
        int lrow = mt * 16 + kq * 4 + r;
        int rm   = min(i0 + lrow, SLEN - 1);
        int col  = wcol + nt * 16 + ml;
        float v = acc[mt][nt][r] + bout[col]
                + bf2f(xb[(size_t)(b * SLEN + rm) * 256 + col]);
        acc[mt][nt][r] = v;
        s_[mt][r] += v;
        q_[mt][r] += v * v;
      }
#pragma unroll
  for (int mt = 0; mt < 4; ++mt)
#pragma unroll
    for (int r = 0; r < 4; ++r) {
#pragma unroll
      for (int off = 8; off; off >>= 1) {
        s_[mt][r] += __shfl_xor(s_[mt][r], off, 16);
        q_[mt][r] += __shfl_xor(q_[mt][r], off, 16);
      }
      if (ml == 0) {
        int lrow = mt * 16 + kq * 4 + r;
        lnred[(w * 64 + lrow) * 3 + 0] = s_[mt][r];
        lnred[(w * 64 + lrow) * 3 + 1] = q_[mt][r];
      }
    }
  __syncthreads();
  if (tid < 64) {
    float s = 0.f, q = 0.f;
#pragma unroll
    for (int i = 0; i < 4; ++i) {
      s += lnred[(i * 64 + tid) * 3 + 0];
      q += lnred[(i * 64 + tid) * 3 + 1];
    }
    float mu  = s * (1.f / 256.f);
    float var = q * (1.f / 256.f) - mu * mu;
    lnstat[tid * 2 + 0] = mu;
    lnstat[tid * 2 + 1] = rsqrtf(var + 1e-5f);
  }
  if (tid == 64) {
    hpc[0] = hpred[0] + hpred[2] + hpred[4] + hpred[6] + fc2b[0];
    hpc[1] = hpred[1] + hpred[3] + hpred[5] + hpred[7];
  }
  __syncthreads();
  floatx4 x1sav[4][4];
#pragma unroll
  for (int mt = 0; mt < 4; ++mt)
#pragma unroll
    for (int r = 0; r < 4; ++r) {
      int lrow = mt * 16 + kq * 4 + r;
      float mu = lnstat[lrow * 2], rr = lnstat[lrow * 2 + 1];
#pragma unroll
      for (int nt = 0; nt < 4; ++nt) {
        int col = wcol + nt * 16 + ml;
        float x1 = (acc[mt][nt][r] - mu) * rr * lnp[col] + lnp[256 + col];
        x1sav[mt][nt][r] = x1;
        CX[lrow * XPAD + col] = f2bf(x1);
      }
    }
  __syncthreads();

  // =============== stage B: h = relu(x1@W1^T + b1) ===============
#pragma unroll
  for (int mt = 0; mt < 4; ++mt)
#pragma unroll
    for (int nt = 0; nt < 4; ++nt) acc[mt][nt] = (floatx4){0.f, 0.f, 0.f, 0.f};
#pragma unroll
  for (int k8 = 0; k8 < 8; ++k8) {
    const int kt = k8 * 32;
    short8 af[4];
#pragma unroll
    for (int mt = 0; mt < 4; ++mt)
      af[mt] = *(const short8*)&CX[(mt * 16 + ml) * XPAD + kt + kq * 8];
#pragma unroll
    for (int nt = 0; nt < 4; ++nt) {
      short8 bf = *(const short8*)(w1 + (size_t)(wcol + nt * 16 + ml) * 256 + kt + kq * 8);
#pragma unroll
      for (int mt = 0; mt < 4; ++mt)
        acc[mt][nt] = __builtin_amdgcn_mfma_f32_16x16x32_bf16(af[mt], bf, acc[mt][nt], 0, 0, 0);
    }
  }
  __syncthreads();
#pragma unroll
  for (int mt = 0; mt < 4; ++mt)
#pragma unroll
    for (int nt = 0; nt < 4; ++nt)
#pragma unroll
      for (int r = 0; r < 4; ++r) {
        int lrow = mt * 16 + kq * 4 + r;
        int col  = wcol + nt * 16 + ml;
        CX[lrow * XPAD + col] = f2bf(fmaxf(acc[mt][nt][r] + b1[col], 0.f));
      }
  __syncthreads();

  // =============== stage C: o = h@W2^T + b2 + x1 -> LN2 + head ===============
#pragma unroll
  for (int mt = 0; mt < 4; ++mt)
#pragma unroll
    for (int nt = 0; nt < 4; ++nt) acc[mt][nt] = (floatx4){0.f, 0.f, 0.f, 0.f};
#pragma unroll
  for (int k8 = 0; k8 < 8; ++k8) {
    const int kt = k8 * 32;
    short8 af[4];
#pragma unroll
    for (int mt = 0; mt < 4; ++mt)
      af[mt] = *(const short8*)&CX[(mt * 16 + ml) * XPAD + kt + kq * 8];
#pragma unroll
    for (int nt = 0; nt < 4; ++nt) {
      short8 bf = *(const short8*)(w2 + (size_t)(wcol + nt * 16 + ml) * 256 + kt + kq * 8);
#pragma unroll
      for (int mt = 0; mt < 4; ++mt)
        acc[mt][nt] = __builtin_amdgcn_mfma_f32_16x16x32_bf16(af[mt], bf, acc[mt][nt], 0, 0, 0);
    }
  }
  float ss[4][4], qq[4][4], dd[4][4];
#pragma unroll
  for (int mt = 0; mt < 4; ++mt)
#pragma unroll
    for (int r = 0; r < 4; ++r) { ss[mt][r] = 0.f; qq[mt][r] = 0.f; dd[mt][r] = 0.f; }
#pragma unroll
  for (int mt = 0; mt < 4; ++mt)
#pragma unroll
    for (int nt = 0; nt < 4; ++nt)
#pragma unroll
      for (int r = 0; r < 4; ++r) {
        int col = wcol + nt * 16 + ml;
        float v = acc[mt][nt][r] + b2[col] + x1sav[mt][nt][r];
        ss[mt][r] += v;
        qq[mt][r] += v * v;
        dd[mt][r] += v * c1s[col];
      }
#pragma unroll
  for (int mt = 0; mt < 4; ++mt)
#pragma unroll
    for (int r = 0; r < 4; ++r) {
#pragma unroll
      for (int off = 8; off; off >>= 1) {
        ss[mt][r] += __shfl_xor(ss[mt][r], off, 16);
        qq[mt][r] += __shfl_xor(qq[mt][r], off, 16);
        dd[mt][r] += __shfl_xor(dd[mt][r], off, 16);
      }
      if (ml == 0) {
        int lrow = mt * 16 + kq * 4 + r;
        lnred[(w * 64 + lrow) * 3 + 0] = ss[mt][r];
        lnred[(w * 64 + lrow) * 3 + 1] = qq[mt][r];
        lnred[(w * 64 + lrow) * 3 + 2] = dd[mt][r];
      }
    }
  __syncthreads();
  if (tid < 64 && i0 + tid < SLEN) {
    float s = 0.f, q = 0.f, d = 0.f;
#pragma unroll
    for (int i = 0; i < 4; ++i) {
      s += lnred[(i * 64 + tid) * 3 + 0];
      q += lnred[(i * 64 + tid) * 3 + 1];
      d += lnred[(i * 64 + tid) * 3 + 2];
    }
    float mu  = s * (1.f / 256.f);
    float var = q * (1.f / 256.f) - mu * mu;
    float rr  = rsqrtf(var + 1e-5f);
    out[(size_t)b * SLEN + i0 + tid] = rr * (d - mu * hpc[1]) + hpc[0];
  }
}

extern "C" void kernel_launch(void* const* d_in, const int* in_sizes, int n_in,
                              void* d_out, int out_size, void* d_ws, size_t ws_size,
                              hipStream_t stream) {
  const float* src        = (const float*)d_in[0];
  // d_in[1] = input_lengths (unused)
  const float* W_enc      = (const float*)d_in[2];
  const float* b_enc      = (const float*)d_in[3];
  const float* in_proj_w  = (const float*)d_in[4];
  const float* in_proj_b  = (const float*)d_in[5];
  const float* out_proj_w = (const float*)d_in[6];
  const float* out_proj_b = (const float*)d_in[7];
  const float* ln1_w      = (const float*)d_in[8];
  const float* ln1_b      = (const float*)d_in[9];
  const float* lin1_w     = (const float*)d_in[10];
  const float* lin1_b     = (const float*)d_in[11];
  const float* lin2_w     = (const float*)d_in[12];
  const float* lin2_b     = (const float*)d_in[13];
  const float* ln2_w      = (const float*)d_in[14];
  const float* ln2_b      = (const float*)d_in[15];
  const float* fc1_w      = (const float*)d_in[16];
  const float* fc1_b      = (const float*)d_in[17];
  const float* fc2_w      = (const float*)d_in[18];
  const float* fc2_b      = (const float*)d_in[19];

  char* p = (char*)d_ws;
  unsigned short* xb   = (unsigned short*)p;  p += (size_t)MTOK * 256 * 2;
  unsigned short* qkvb = (unsigned short*)p;  p += (size_t)MTOK * 768 * 2;
  unsigned short* wencb= (unsigned short*)p;  p += 256 * 256 * 2;
  unsigned short* wqkb = (unsigned short*)p;  p += 768 * 256 * 2;
  unsigned short* woutb= (unsigned short*)p;  p += 256 * 256 * 2;
  unsigned short* wl1b = (unsigned short*)p;  p += 256 * 256 * 2;
  unsigned short* wl2b = (unsigned short*)p;  p += 256 * 256 * 2;

  // dispatch 1: weight cvt only
  k_prep<<<448, 256, 0, stream>>>(W_enc, wencb, in_proj_w, wqkb,
                                  out_proj_w, woutb, lin1_w, wl1b, lin2_w, wl2b);
  // dispatch 2: encoder + qkv (R9 structure, posenc inline)
  k_pre<<<MTOK / 64, 256, 0, stream>>>(src, wencb, b_enc, wqkb, in_proj_b, xb, qkvb);
  // dispatch 3: attention + o-proj + LN1 + FFN + LN2 + head (bf16 weights)
  k_ap<<<dim3((SLEN + 63) / 64, BATCH), 256, 0, stream>>>(
      qkvb, xb, woutb, out_proj_b, ln1_w, ln1_b,
      wl1b, lin1_b, wl2b, lin2_b,
      fc1_w, fc1_b, fc2_w, fc2_b, ln2_w, ln2_b, (float*)d_out);
}